// Round 1
// baseline (544.578 us; speedup 1.0000x reference)
//
#include <hip/hip_runtime.h>
#include <stdint.h>

#define B_ 64
#define Q_ 900
#define T_ 100
#define C_ 256
#define INF_ 1e9f

// ---------------------------------------------------------------------------
// Kernel 1: cost matrix.
// cost[b,q,t] = -logits[b,q,lab[b,t]] + L1_cxcywh(pbox, tbox) - GIoU(xyxy)
// Writes [B,Q,T] (output layout) and optionally [B,T,Q] (solver layout).
// ---------------------------------------------------------------------------
__global__ __launch_bounds__(256) void cost_kernel(
    const float* __restrict__ logits,   // [B,Q,C]
    const float* __restrict__ pboxes,   // [B,Q,4] cxcywh
    const int*   __restrict__ tlabels,  // [B,T]
    const float* __restrict__ tboxes,   // [B,T,4] cxcywh
    float* __restrict__ cost_out,       // [B,Q,T]
    float* __restrict__ costT_out)      // [B,T,Q] or nullptr
{
    const int b = blockIdx.y;
    const int q = blockIdx.x * 256 + threadIdx.x;

    __shared__ float s_cx[T_][4];   // raw cxcywh (for L1)
    __shared__ float s_xy[T_][4];   // converted xyxy
    __shared__ float s_area[T_];
    __shared__ int   s_lab[T_];

    for (int t = threadIdx.x; t < T_; t += 256) {
        float cx = tboxes[((size_t)b * T_ + t) * 4 + 0];
        float cy = tboxes[((size_t)b * T_ + t) * 4 + 1];
        float w  = tboxes[((size_t)b * T_ + t) * 4 + 2];
        float h  = tboxes[((size_t)b * T_ + t) * 4 + 3];
        s_cx[t][0] = cx; s_cx[t][1] = cy; s_cx[t][2] = w; s_cx[t][3] = h;
        float x0 = cx - 0.5f * w, y0 = cy - 0.5f * h;
        float x1 = cx + 0.5f * w, y1 = cy + 0.5f * h;
        s_xy[t][0] = x0; s_xy[t][1] = y0; s_xy[t][2] = x1; s_xy[t][3] = y1;
        s_area[t] = (x1 - x0) * (y1 - y0);
        s_lab[t]  = tlabels[b * T_ + t];
    }
    __syncthreads();
    if (q >= Q_) return;

    const float4 pb = *reinterpret_cast<const float4*>(pboxes + ((size_t)b * Q_ + q) * 4);
    const float pcx = pb.x, pcy = pb.y, pw = pb.z, ph = pb.w;
    const float ax0 = pcx - 0.5f * pw, ay0 = pcy - 0.5f * ph;
    const float ax1 = pcx + 0.5f * pw, ay1 = pcy + 0.5f * ph;
    const float area_a = (ax1 - ax0) * (ay1 - ay0);
    const float* lrow = logits + ((size_t)b * Q_ + q) * C_;

    float* orow = cost_out + ((size_t)b * Q_ + q) * T_;

    for (int t = 0; t < T_; ++t) {
        float cls = -lrow[s_lab[t]];
        float l1 = fabsf(pcx - s_cx[t][0]) + fabsf(pcy - s_cx[t][1])
                 + fabsf(pw  - s_cx[t][2]) + fabsf(ph  - s_cx[t][3]);
        float bx0 = s_xy[t][0], by0 = s_xy[t][1], bx1 = s_xy[t][2], by1 = s_xy[t][3];
        float ltx = fmaxf(ax0, bx0), lty = fmaxf(ay0, by0);
        float rbx = fminf(ax1, bx1), rby = fminf(ay1, by1);
        float wx = fmaxf(rbx - ltx, 0.0f), wy = fmaxf(rby - lty, 0.0f);
        float inter = wx * wy;
        float uni = area_a + s_area[t] - inter;
        float iou = inter / uni;
        float ex0 = fminf(ax0, bx0), ey0 = fminf(ay0, by0);
        float ex1 = fmaxf(ax1, bx1), ey1 = fmaxf(ay1, by1);
        float ew = fmaxf(ex1 - ex0, 0.0f), eh = fmaxf(ey1 - ey0, 0.0f);
        float enc = ew * eh;
        float giou = iou - (enc - uni) / enc;
        float c = cls + l1 - giou;
        orow[t] = c;
        if (costT_out) costT_out[(size_t)b * T_ * Q_ + (size_t)t * Q_ + q] = c;
    }
}

// ---------------------------------------------------------------------------
// Kernel 2: exact Hungarian (Jonker-Volgenant shortest augmenting path) on
// cost^T [T,Q] per batch. One 256-thread block per batch. Mirrors the
// reference's arithmetic and first-index argmin tie-break exactly.
// ---------------------------------------------------------------------------
__global__ __launch_bounds__(256) void hung_kernel(
    const float* __restrict__ cost,   // base pointer
    int64_t rowStride,                // stride between rows (target index)
    int64_t colStride,                // stride between cols (query index)
    int64_t batchStride,
    float* __restrict__ out_pred,     // [B,T] as float
    float* __restrict__ out_tgt)      // [B,T] as float
{
    const int b = blockIdx.x;
    const int tid = threadIdx.x;
    const int lane = tid & 63;
    const int wave = tid >> 6;

    __shared__ float v[Q_];
    __shared__ float minv[Q_];
    __shared__ float u[T_ + 1];
    __shared__ int   way[Q_];
    __shared__ int   p[Q_];
    __shared__ unsigned char used[Q_];
    __shared__ int   col[T_];
    __shared__ float red_v[4];
    __shared__ int   red_j[4];
    __shared__ int   s_i0, s_j1;
    __shared__ float s_delta;

    for (int j = tid; j < Q_; j += 256) { v[j] = 0.0f; p[j] = -1; }
    for (int t = tid; t <= T_; t += 256) u[t] = 0.0f;
    __syncthreads();

    const float* cb = cost + (int64_t)b * batchStride;

    for (int i = 0; i < T_; ++i) {
        for (int j = tid; j < Q_; j += 256) { minv[j] = INF_; used[j] = 0; way[j] = Q_; }
        int j0 = Q_;   // virtual start column
        __syncthreads();

        while (true) {
            if (tid == 0) {
                int i0;
                if (j0 == Q_) { i0 = i; }
                else          { used[j0] = 1; i0 = p[j0]; }
                s_i0 = i0;
            }
            __syncthreads();
            const int i0 = s_i0;
            const float ui0 = u[i0];
            const float* row = cb + (int64_t)i0 * rowStride;

            float best = INF_;
            int   bj = Q_;
            for (int j = tid; j < Q_; j += 256) {
                if (!used[j]) {
                    float cur = row[(int64_t)j * colStride] - ui0 - v[j];
                    float m = minv[j];
                    if (cur < m) { m = cur; minv[j] = cur; way[j] = j0; }
                    if (m < best) { best = m; bj = j; }
                }
            }
            // wave reduce: min value, tie -> smaller index (matches jnp.argmin)
            for (int off = 32; off > 0; off >>= 1) {
                float ov = __shfl_down(best, (unsigned)off, 64);
                int   oj = __shfl_down(bj,   (unsigned)off, 64);
                if (ov < best || (ov == best && oj < bj)) { best = ov; bj = oj; }
            }
            if (lane == 0) { red_v[wave] = best; red_j[wave] = bj; }
            __syncthreads();
            if (tid == 0) {
                float dv = red_v[0]; int dj = red_j[0];
                for (int w2 = 1; w2 < 4; ++w2) {
                    if (red_v[w2] < dv || (red_v[w2] == dv && red_j[w2] < dj)) {
                        dv = red_v[w2]; dj = red_j[w2];
                    }
                }
                s_delta = dv; s_j1 = dj;
                u[i] += dv;   // virtual column holds current row i
            }
            __syncthreads();
            const float delta = s_delta;
            const int j1 = s_j1;
            for (int j = tid; j < Q_; j += 256) {
                if (used[j]) { u[p[j]] += delta; v[j] -= delta; }  // distinct rows: no race
                else         { minv[j] -= delta; }
            }
            __syncthreads();
            j0 = j1;
            if (p[j1] < 0) break;   // reached a free column -> augment
        }

        if (tid == 0) {
            int jj = j0;
            while (true) {
                int jp = way[jj];
                if (jp == Q_) { p[jj] = i; break; }
                p[jj] = p[jp];
                jj = jp;
            }
        }
        __syncthreads();
    }

    // col[t] = query assigned to target t
    for (int j = tid; j < Q_; j += 256) {
        int r = p[j];
        if (r >= 0) col[r] = j;
    }
    __syncthreads();
    if (tid < T_) {
        int cj = col[tid];
        int rank = 0;
        for (int t2 = 0; t2 < T_; ++t2) rank += (col[t2] < cj) ? 1 : 0;
        out_pred[b * T_ + rank] = (float)cj;
        out_tgt [b * T_ + rank] = (float)tid;
    }
}

extern "C" void kernel_launch(void* const* d_in, const int* in_sizes, int n_in,
                              void* d_out, int out_size, void* d_ws, size_t ws_size,
                              hipStream_t stream) {
    const float* logits  = (const float*)d_in[0];   // [B,Q,C]
    const float* pboxes  = (const float*)d_in[1];   // [B,Q,4]
    const int*   tlabels = (const int*)d_in[2];     // [B,T]
    const float* tboxes  = (const float*)d_in[3];   // [B,T,4]

    float* out      = (float*)d_out;
    float* cost     = out;                                   // [B,Q,T]
    float* out_pred = out + (size_t)B_ * Q_ * T_;            // [B,T]
    float* out_tgt  = out_pred + (size_t)B_ * T_;            // [B,T]

    float* costT = nullptr;
    const size_t needT = (size_t)B_ * T_ * Q_ * sizeof(float);
    if (ws_size >= needT) costT = (float*)d_ws;              // [B,T,Q]

    dim3 gridc((Q_ + 255) / 256, B_);
    cost_kernel<<<gridc, 256, 0, stream>>>(logits, pboxes, tlabels, tboxes, cost, costT);

    if (costT) {
        hung_kernel<<<B_, 256, 0, stream>>>(costT, (int64_t)Q_, (int64_t)1,
                                            (int64_t)T_ * Q_, out_pred, out_tgt);
    } else {
        // fall back to strided reads straight out of the [B,Q,T] cost output
        hung_kernel<<<B_, 256, 0, stream>>>(cost, (int64_t)1, (int64_t)T_,
                                            (int64_t)Q_ * T_, out_pred, out_tgt);
    }
}

// Round 2
// 350.866 us; speedup vs baseline: 1.5521x; 1.5521x over previous
//
#include <hip/hip_runtime.h>
#include <stdint.h>

#define B_ 64
#define Q_ 900
#define T_ 100
#define C_ 256
#define INF_ 1e9f

// ---------------------------------------------------------------------------
// Kernel 1: cost matrix. Thread per query q; all 100 target costs computed
// into registers, then stored twice:
//   costT [B,T,Q]  - coalesced scalar stores (solver layout)
//   cost  [B,Q,T]  - float4 stores (output layout)
// ---------------------------------------------------------------------------
__global__ __launch_bounds__(256) void cost_kernel(
    const float* __restrict__ logits,   // [B,Q,C]
    const float* __restrict__ pboxes,   // [B,Q,4] cxcywh
    const int*   __restrict__ tlabels,  // [B,T]
    const float* __restrict__ tboxes,   // [B,T,4] cxcywh
    float* __restrict__ cost_out,       // [B,Q,T]
    float* __restrict__ costT_out)      // [B,T,Q]
{
    const int b = blockIdx.y;
    const int q = blockIdx.x * 256 + threadIdx.x;

    __shared__ float s_cx[T_][4];   // raw cxcywh (for L1)
    __shared__ float s_xy[T_][4];   // converted xyxy
    __shared__ float s_area[T_];
    __shared__ int   s_lab[T_];

    for (int t = threadIdx.x; t < T_; t += 256) {
        const float4 tb = *reinterpret_cast<const float4*>(tboxes + ((size_t)b * T_ + t) * 4);
        float cx = tb.x, cy = tb.y, w = tb.z, h = tb.w;
        s_cx[t][0] = cx; s_cx[t][1] = cy; s_cx[t][2] = w; s_cx[t][3] = h;
        float x0 = cx - 0.5f * w, y0 = cy - 0.5f * h;
        float x1 = cx + 0.5f * w, y1 = cy + 0.5f * h;
        s_xy[t][0] = x0; s_xy[t][1] = y0; s_xy[t][2] = x1; s_xy[t][3] = y1;
        s_area[t] = (x1 - x0) * (y1 - y0);
        s_lab[t]  = tlabels[b * T_ + t];
    }
    __syncthreads();
    if (q >= Q_) return;

    const float4 pb = *reinterpret_cast<const float4*>(pboxes + ((size_t)b * Q_ + q) * 4);
    const float pcx = pb.x, pcy = pb.y, pw = pb.z, ph = pb.w;
    const float ax0 = pcx - 0.5f * pw, ay0 = pcy - 0.5f * ph;
    const float ax1 = pcx + 0.5f * pw, ay1 = pcy + 0.5f * ph;
    const float area_a = (ax1 - ax0) * (ay1 - ay0);
    const float* __restrict__ lrow = logits + ((size_t)b * Q_ + q) * C_;

    float c[T_];
    #pragma unroll
    for (int t = 0; t < T_; ++t) {
        float cls = -lrow[s_lab[t]];
        float l1 = fabsf(pcx - s_cx[t][0]) + fabsf(pcy - s_cx[t][1])
                 + fabsf(pw  - s_cx[t][2]) + fabsf(ph  - s_cx[t][3]);
        float bx0 = s_xy[t][0], by0 = s_xy[t][1], bx1 = s_xy[t][2], by1 = s_xy[t][3];
        float ltx = fmaxf(ax0, bx0), lty = fmaxf(ay0, by0);
        float rbx = fminf(ax1, bx1), rby = fminf(ay1, by1);
        float wx = fmaxf(rbx - ltx, 0.0f), wy = fmaxf(rby - lty, 0.0f);
        float inter = wx * wy;
        float uni = area_a + s_area[t] - inter;
        float iou = inter / uni;
        float ex0 = fminf(ax0, bx0), ey0 = fminf(ay0, by0);
        float ex1 = fmaxf(ax1, bx1), ey1 = fmaxf(ay1, by1);
        float ew = fmaxf(ex1 - ex0, 0.0f), eh = fmaxf(ey1 - ey0, 0.0f);
        float enc = ew * eh;
        float giou = iou - (enc - uni) / enc;
        c[t] = cls + l1 - giou;
    }

    // solver layout: coalesced (lane-contiguous in q)
    float* __restrict__ ct = costT_out + (size_t)b * T_ * Q_ + q;
    #pragma unroll
    for (int t = 0; t < T_; ++t) ct[(size_t)t * Q_] = c[t];

    // output layout: float4 stores (row is 400B, 16B-aligned)
    float4* __restrict__ orow = reinterpret_cast<float4*>(cost_out + ((size_t)b * Q_ + q) * T_);
    #pragma unroll
    for (int t4 = 0; t4 < T_ / 4; ++t4)
        orow[t4] = make_float4(c[4*t4], c[4*t4+1], c[4*t4+2], c[4*t4+3]);
}

// ---------------------------------------------------------------------------
// Kernel 2: exact Hungarian with greedy dual-feasible warm start.
//   Phase 1: u[i] = min_j cost[i][j] (4 waves scan rows in parallel),
//            greedy-assign row -> argmin column if free.
//   Phase 2: Jonker-Volgenant shortest augmenting path for the ~T^2/2Q
//            conflicted rows only. Exact optimum; unique a.s. => matches ref.
// ---------------------------------------------------------------------------
__global__ __launch_bounds__(256) void hung_kernel(
    const float* __restrict__ cost,   // base pointer
    int64_t rowStride, int64_t colStride, int64_t batchStride,
    float* __restrict__ out_pred,     // [B,T] as float
    float* __restrict__ out_tgt)      // [B,T] as float
{
    const int b = blockIdx.x;
    const int tid = threadIdx.x;
    const int lane = tid & 63;
    const int wave = tid >> 6;
    const float* __restrict__ cb = cost + (int64_t)b * batchStride;

    __shared__ float v[Q_];
    __shared__ float minv[Q_];
    __shared__ float u[T_];
    __shared__ int   way[Q_];
    __shared__ int   p[Q_];
    __shared__ unsigned char used[Q_];
    __shared__ int   ji[T_];
    __shared__ int   pend[T_];
    __shared__ int   col[T_];
    __shared__ float red_v[4];
    __shared__ int   red_j[4];
    __shared__ int   s_npend, s_i0, s_j1;
    __shared__ float s_delta;

    for (int j = tid; j < Q_; j += 256) { v[j] = 0.0f; p[j] = -1; }
    __syncthreads();

    // ---- Phase 1: per-row minima (waves cover rows round-robin) ----
    for (int i = wave; i < T_; i += 4) {
        const float* row = cb + (int64_t)i * rowStride;
        float best = INF_; int bj = Q_;
        for (int j = lane; j < Q_; j += 64) {
            float val = row[(int64_t)j * colStride];
            if (val < best) { best = val; bj = j; }
        }
        for (int off = 1; off < 64; off <<= 1) {
            float ov = __shfl_xor(best, off, 64);
            int   oj = __shfl_xor(bj,   off, 64);
            if (ov < best || (ov == best && oj < bj)) { best = ov; bj = oj; }
        }
        if (lane == 0) { u[i] = best; ji[i] = bj; }
    }
    __syncthreads();

    // ---- greedy assignment (serial, tiny) ----
    if (tid == 0) {
        int np = 0;
        for (int i = 0; i < T_; ++i) {
            int j = ji[i];
            if (p[j] < 0) p[j] = i;
            else pend[np++] = i;
        }
        s_npend = np;
    }
    __syncthreads();
    const int npend = s_npend;

    // ---- Phase 2: shortest augmenting path for conflicted rows ----
    for (int k = 0; k < npend; ++k) {
        const int isrc = pend[k];
        for (int j = tid; j < Q_; j += 256) { minv[j] = INF_; used[j] = 0; way[j] = Q_; }
        int j0 = Q_;   // virtual start column
        __syncthreads();

        while (true) {
            if (tid == 0) {
                int i0;
                if (j0 == Q_) { i0 = isrc; }
                else          { used[j0] = 1; i0 = p[j0]; }
                s_i0 = i0;
            }
            __syncthreads();
            const int i0 = s_i0;
            const float ui0 = u[i0];
            const float* row = cb + (int64_t)i0 * rowStride;

            float best = INF_; int bj = Q_;
            for (int j = tid; j < Q_; j += 256) {
                if (!used[j]) {
                    float cur = row[(int64_t)j * colStride] - ui0 - v[j];
                    float m = minv[j];
                    if (cur < m) { m = cur; minv[j] = cur; way[j] = j0; }
                    if (m < best) { best = m; bj = j; }
                }
            }
            for (int off = 1; off < 64; off <<= 1) {
                float ov = __shfl_xor(best, off, 64);
                int   oj = __shfl_xor(bj,   off, 64);
                if (ov < best || (ov == best && oj < bj)) { best = ov; bj = oj; }
            }
            if (lane == 0) { red_v[wave] = best; red_j[wave] = bj; }
            __syncthreads();
            if (tid == 0) {
                float dv = red_v[0]; int dj = red_j[0];
                for (int w2 = 1; w2 < 4; ++w2) {
                    if (red_v[w2] < dv || (red_v[w2] == dv && red_j[w2] < dj)) {
                        dv = red_v[w2]; dj = red_j[w2];
                    }
                }
                s_delta = dv; s_j1 = dj;
                u[isrc] += dv;   // virtual column holds the augmenting row
            }
            __syncthreads();
            const float delta = s_delta;
            const int j1 = s_j1;
            for (int j = tid; j < Q_; j += 256) {
                if (used[j]) { u[p[j]] += delta; v[j] -= delta; }  // distinct rows: no race
                else         { minv[j] -= delta; }
            }
            __syncthreads();
            j0 = j1;
            if (p[j1] < 0) break;   // reached a free column -> augment
        }

        if (tid == 0) {
            int jj = j0;
            while (true) {
                int jp = way[jj];
                if (jp == Q_) { p[jj] = isrc; break; }
                p[jj] = p[jp];
                jj = jp;
            }
        }
        __syncthreads();
    }

    // ---- output: col[t] = query assigned to target t; rank-sort ----
    for (int j = tid; j < Q_; j += 256) {
        int r = p[j];
        if (r >= 0) col[r] = j;
    }
    __syncthreads();
    if (tid < T_) {
        int cj = col[tid];
        int rank = 0;
        for (int t2 = 0; t2 < T_; ++t2) rank += (col[t2] < cj) ? 1 : 0;
        out_pred[b * T_ + rank] = (float)cj;
        out_tgt [b * T_ + rank] = (float)tid;
    }
}

extern "C" void kernel_launch(void* const* d_in, const int* in_sizes, int n_in,
                              void* d_out, int out_size, void* d_ws, size_t ws_size,
                              hipStream_t stream) {
    const float* logits  = (const float*)d_in[0];   // [B,Q,C]
    const float* pboxes  = (const float*)d_in[1];   // [B,Q,4]
    const int*   tlabels = (const int*)d_in[2];     // [B,T]
    const float* tboxes  = (const float*)d_in[3];   // [B,T,4]

    float* out      = (float*)d_out;
    float* cost     = out;                                   // [B,Q,T]
    float* out_pred = out + (size_t)B_ * Q_ * T_;            // [B,T]
    float* out_tgt  = out_pred + (size_t)B_ * T_;            // [B,T]

    float* costT = nullptr;
    const size_t needT = (size_t)B_ * T_ * Q_ * sizeof(float);
    if (ws_size >= needT) costT = (float*)d_ws;              // [B,T,Q]

    dim3 gridc((Q_ + 255) / 256, B_);

    if (costT) {
        cost_kernel<<<gridc, 256, 0, stream>>>(logits, pboxes, tlabels, tboxes, cost, costT);
        hung_kernel<<<B_, 256, 0, stream>>>(costT, (int64_t)Q_, (int64_t)1,
                                            (int64_t)T_ * Q_, out_pred, out_tgt);
    } else {
        // no workspace: skip costT (write cost twice to same buffer harmlessly)
        cost_kernel<<<gridc, 256, 0, stream>>>(logits, pboxes, tlabels, tboxes, cost, cost);
        hung_kernel<<<B_, 256, 0, stream>>>(cost, (int64_t)1, (int64_t)T_,
                                            (int64_t)Q_ * T_, out_pred, out_tgt);
    }
}

// Round 3
// 345.513 us; speedup vs baseline: 1.5761x; 1.0155x over previous
//
#include <hip/hip_runtime.h>
#include <stdint.h>

#define B_ 64
#define Q_ 900
#define T_ 100
#define C_ 256
#define INF_ 1e9f
#define TCH 20      // targets per cost-kernel chunk
#define NTC 5       // T_/TCH
#define KSLOT 15    // ceil(Q_/64) column slots per lane in hung kernel

// Orderable-uint encoding of float: preserves < ordering on the uint.
__device__ __forceinline__ unsigned int float_to_ord(float f) {
    unsigned int s = __float_as_uint(f);
    return s ^ ((s & 0x80000000u) ? 0xFFFFFFFFu : 0x80000000u);
}
__device__ __forceinline__ float ord_to_float(unsigned int e) {
    unsigned int s = (e & 0x80000000u) ? (e ^ 0x80000000u) : ~e;
    return __uint_as_float(s);
}

// ---------------------------------------------------------------------------
// Kernel 1: cost matrix, t-chunked for occupancy. Also computes per-row
// (target) min+argmin over q via packed u64 atomicMin -> exact warm-start
// duals for the solver.
// ---------------------------------------------------------------------------
__global__ __launch_bounds__(256) void cost_kernel(
    const float* __restrict__ logits,   // [B,Q,C]
    const float* __restrict__ pboxes,   // [B,Q,4] cxcywh
    const int*   __restrict__ tlabels,  // [B,T]
    const float* __restrict__ tboxes,   // [B,T,4] cxcywh
    float* __restrict__ cost_out,       // [B,Q,T]
    float* __restrict__ costT_out,      // [B,T,Q]
    unsigned long long* __restrict__ ukey)  // [B,T] packed (ordfloat, q)
{
    const int b   = blockIdx.z;
    const int t0  = blockIdx.y * TCH;
    const int tid = threadIdx.x;
    const int q   = blockIdx.x * 256 + tid;
    const int lane = tid & 63;

    __shared__ float s_cx[TCH][4];
    __shared__ float s_xy[TCH][4];
    __shared__ float s_area[TCH];
    __shared__ int   s_lab[TCH];

    for (int t = tid; t < TCH; t += 256) {
        const float4 tb = *reinterpret_cast<const float4*>(tboxes + ((size_t)b * T_ + t0 + t) * 4);
        float cx = tb.x, cy = tb.y, w = tb.z, h = tb.w;
        s_cx[t][0] = cx; s_cx[t][1] = cy; s_cx[t][2] = w; s_cx[t][3] = h;
        float x0 = cx - 0.5f * w, y0 = cy - 0.5f * h;
        float x1 = cx + 0.5f * w, y1 = cy + 0.5f * h;
        s_xy[t][0] = x0; s_xy[t][1] = y0; s_xy[t][2] = x1; s_xy[t][3] = y1;
        s_area[t] = (x1 - x0) * (y1 - y0);
        s_lab[t]  = tlabels[b * T_ + t0 + t];
    }
    __syncthreads();

    const bool qok = (q < Q_);
    float c[TCH];

    if (qok) {
        const float4 pb = *reinterpret_cast<const float4*>(pboxes + ((size_t)b * Q_ + q) * 4);
        const float pcx = pb.x, pcy = pb.y, pw = pb.z, ph = pb.w;
        const float ax0 = pcx - 0.5f * pw, ay0 = pcy - 0.5f * ph;
        const float ax1 = pcx + 0.5f * pw, ay1 = pcy + 0.5f * ph;
        const float area_a = (ax1 - ax0) * (ay1 - ay0);
        const float* __restrict__ lrow = logits + ((size_t)b * Q_ + q) * C_;

        #pragma unroll
        for (int tt = 0; tt < TCH; ++tt) {
            float cls = -lrow[s_lab[tt]];
            float l1 = fabsf(pcx - s_cx[tt][0]) + fabsf(pcy - s_cx[tt][1])
                     + fabsf(pw  - s_cx[tt][2]) + fabsf(ph  - s_cx[tt][3]);
            float bx0 = s_xy[tt][0], by0 = s_xy[tt][1], bx1 = s_xy[tt][2], by1 = s_xy[tt][3];
            float ltx = fmaxf(ax0, bx0), lty = fmaxf(ay0, by0);
            float rbx = fminf(ax1, bx1), rby = fminf(ay1, by1);
            float wx = fmaxf(rbx - ltx, 0.0f), wy = fmaxf(rby - lty, 0.0f);
            float inter = wx * wy;
            float uni = area_a + s_area[tt] - inter;
            float iou = inter / uni;
            float ex0 = fminf(ax0, bx0), ey0 = fminf(ay0, by0);
            float ex1 = fmaxf(ax1, bx1), ey1 = fmaxf(ay1, by1);
            float ew = fmaxf(ex1 - ex0, 0.0f), eh = fmaxf(ey1 - ey0, 0.0f);
            float enc = ew * eh;
            float giou = iou - (enc - uni) / enc;
            c[tt] = cls + l1 - giou;
        }

        // solver layout [B,T,Q]: coalesced scalar stores
        float* __restrict__ ct = costT_out + (size_t)b * T_ * Q_ + (size_t)t0 * Q_ + q;
        #pragma unroll
        for (int tt = 0; tt < TCH; ++tt) ct[(size_t)tt * Q_] = c[tt];

        // output layout [B,Q,T]: float4 stores (t0*4 bytes offset is 16B aligned)
        float4* __restrict__ orow = reinterpret_cast<float4*>(cost_out + ((size_t)b * Q_ + q) * T_ + t0);
        #pragma unroll
        for (int t4 = 0; t4 < TCH / 4; ++t4)
            orow[t4] = make_float4(c[4*t4], c[4*t4+1], c[4*t4+2], c[4*t4+3]);
    }

    // per-row min+argmin over this block's q-range -> global atomicMin
    #pragma unroll
    for (int tt = 0; tt < TCH; ++tt) {
        float val = qok ? c[tt] : INF_;
        int   j   = qok ? q : Q_;
        #pragma unroll
        for (int off = 1; off < 64; off <<= 1) {
            float ov = __shfl_xor(val, off, 64);
            int   oj = __shfl_xor(j,   off, 64);
            if (ov < val || (ov == val && oj < j)) { val = ov; j = oj; }
        }
        if (lane == 0 && j < Q_) {
            unsigned long long key = ((unsigned long long)float_to_ord(val) << 32) | (unsigned int)j;
            atomicMin(&ukey[b * T_ + t0 + tt], key);
        }
    }
}

// ---------------------------------------------------------------------------
// Kernel 2: exact Hungarian (JV SAP) with greedy warm start from ukey.
// ONE WAVE (64 threads) per batch: __syncthreads is ~free, per-lane column
// state (v, minv, used) lives in registers; p/way/u in LDS.
// ---------------------------------------------------------------------------
__global__ __launch_bounds__(64) void hung_kernel(
    const float* __restrict__ costT,              // [B,T,Q]
    const unsigned long long* __restrict__ ukey,  // [B,T] or nullptr
    float* __restrict__ out_pred,                 // [B,T] as float
    float* __restrict__ out_tgt)                  // [B,T] as float
{
    const int b = blockIdx.x;
    const int lane = threadIdx.x;
    const float* __restrict__ cb = costT + (size_t)b * T_ * Q_;

    __shared__ float u[T_];
    __shared__ int   p[Q_];
    __shared__ int   way[Q_];
    __shared__ int   ji[T_];
    __shared__ int   pend[T_];
    __shared__ int   col[T_];
    __shared__ int   s_np;

    float v[KSLOT], minv[KSLOT];

    for (int k = 0; k < KSLOT; ++k) {
        int j = k * 64 + lane;
        if (j < Q_) p[j] = -1;
        v[k] = 0.0f;
    }

    if (ukey) {
        for (int t = lane; t < T_; t += 64) {
            unsigned long long key = ukey[b * T_ + t];
            u[t]  = ord_to_float((unsigned int)(key >> 32));
            ji[t] = (int)(key & 0xFFFFFFFFu);
        }
        __syncthreads();
    } else {
        // fallback: serial per-row scans
        for (int i = 0; i < T_; ++i) {
            const float* row = cb + (size_t)i * Q_;
            float best = INF_; int bj = Q_;
            for (int k = 0; k < KSLOT; ++k) {
                int j = k * 64 + lane;
                if (j < Q_) {
                    float val = row[j];
                    if (val < best) { best = val; bj = j; }
                }
            }
            #pragma unroll
            for (int off = 1; off < 64; off <<= 1) {
                float ov = __shfl_xor(best, off, 64);
                int   oj = __shfl_xor(bj,   off, 64);
                if (ov < best || (ov == best && oj < bj)) { best = ov; bj = oj; }
            }
            if (lane == 0) { u[i] = best; ji[i] = bj; }
        }
        __syncthreads();
    }

    // greedy assignment (lane 0, tiny)
    if (lane == 0) {
        int np = 0;
        for (int i = 0; i < T_; ++i) {
            int j = ji[i];
            if (p[j] < 0) p[j] = i;
            else pend[np++] = i;
        }
        s_np = np;
    }
    __syncthreads();
    const int npend = s_np;

    // shortest augmenting path for conflicted rows
    for (int kk = 0; kk < npend; ++kk) {
        const int isrc = pend[kk];   // uniform LDS read
        unsigned int used = 0;
        for (int k = 0; k < KSLOT; ++k) minv[k] = INF_;
        int j0 = Q_;
        __syncthreads();

        while (true) {
            int i0;
            if (j0 == Q_) i0 = isrc;
            else {
                if (lane == (j0 & 63)) used |= 1u << (j0 >> 6);
                i0 = p[j0];          // uniform LDS read
            }
            const float ui0 = u[i0]; // uniform LDS read
            const float* __restrict__ row = cb + (size_t)i0 * Q_;

            float best = INF_; int bj = Q_;
            #pragma unroll
            for (int k = 0; k < KSLOT; ++k) {
                int j = k * 64 + lane;
                if (j < Q_ && !((used >> k) & 1u)) {
                    float cur = row[j] - ui0 - v[k];
                    if (cur < minv[k]) { minv[k] = cur; way[j] = j0; }
                    float m = minv[k];
                    if (m < best) { best = m; bj = j; }
                }
            }
            #pragma unroll
            for (int off = 1; off < 64; off <<= 1) {
                float ov = __shfl_xor(best, off, 64);
                int   oj = __shfl_xor(bj,   off, 64);
                if (ov < best || (ov == best && oj < bj)) { best = ov; bj = oj; }
            }
            const float delta = best;  // uniform (butterfly -> all lanes agree)
            const int   j1    = bj;

            if (lane == 0) u[isrc] += delta;
            #pragma unroll
            for (int k = 0; k < KSLOT; ++k) {
                int j = k * 64 + lane;
                if (j < Q_) {
                    if ((used >> k) & 1u) {
                        int r = p[j];          // matched row (distinct per column)
                        u[r] += delta;         // distinct LDS addresses: no race
                        v[k] -= delta;
                    } else {
                        minv[k] -= delta;
                    }
                }
            }
            __syncthreads();
            j0 = j1;
            if (p[j1] < 0) break;    // uniform LDS read
        }

        // augment: walk predecessor chain (uniform; lane 0 writes)
        int jj = j0;
        while (true) {
            int jp = way[jj];        // uniform LDS read
            if (lane == 0) p[jj] = (jp == Q_) ? isrc : p[jp];
            __syncthreads();
            if (jp == Q_) break;
            jj = jp;
        }
        __syncthreads();
    }

    // outputs: col[t] = query assigned to target t; rank-sort ascending by query
    for (int k = 0; k < KSLOT; ++k) {
        int j = k * 64 + lane;
        if (j < Q_) {
            int r = p[j];
            if (r >= 0) col[r] = j;
        }
    }
    __syncthreads();
    for (int t = lane; t < T_; t += 64) {
        int cj = col[t];
        int rank = 0;
        for (int t2 = 0; t2 < T_; ++t2) rank += (col[t2] < cj) ? 1 : 0;
        out_pred[b * T_ + rank] = (float)cj;
        out_tgt [b * T_ + rank] = (float)t;
    }
}

extern "C" void kernel_launch(void* const* d_in, const int* in_sizes, int n_in,
                              void* d_out, int out_size, void* d_ws, size_t ws_size,
                              hipStream_t stream) {
    const float* logits  = (const float*)d_in[0];   // [B,Q,C]
    const float* pboxes  = (const float*)d_in[1];   // [B,Q,4]
    const int*   tlabels = (const int*)d_in[2];     // [B,T]
    const float* tboxes  = (const float*)d_in[3];   // [B,T,4]

    float* out      = (float*)d_out;
    float* cost     = out;                                   // [B,Q,T]
    float* out_pred = out + (size_t)B_ * Q_ * T_;            // [B,T]
    float* out_tgt  = out_pred + (size_t)B_ * T_;            // [B,T]

    const size_t costT_bytes = (size_t)B_ * T_ * Q_ * sizeof(float);   // 23,040,000
    const size_t ukey_bytes  = (size_t)B_ * T_ * sizeof(unsigned long long);

    float* costT = (float*)d_ws;                             // [B,T,Q]
    unsigned long long* ukey = nullptr;
    if (ws_size >= costT_bytes + ukey_bytes)
        ukey = (unsigned long long*)((char*)d_ws + costT_bytes);

    if (ukey) hipMemsetAsync(ukey, 0xFF, ukey_bytes, stream);  // all-ones = atomicMin identity

    dim3 gridc(4, NTC, B_);   // 4 q-chunks x 5 t-chunks x 64 batches
    cost_kernel<<<gridc, 256, 0, stream>>>(logits, pboxes, tlabels, tboxes,
                                           cost, costT, ukey);
    hung_kernel<<<B_, 64, 0, stream>>>(costT, ukey, out_pred, out_tgt);
}